// Round 1
// baseline (404.344 us; speedup 1.0000x reference)
//
#include <hip/hip_runtime.h>
#include <math.h>

#define N_ANCH 13824   // 24*24*24
#define TPB 256
#define PER_T 54       // 13824 / 256
#define K_TOP 60
#define K_NMS 20
#define AVG_TOPN 7

__global__ __launch_bounds__(TPB)
void detpp_kernel(const float* __restrict__ Cls,
                  const float* __restrict__ Shp,
                  const float* __restrict__ Off,
                  float* __restrict__ Out) {
  // Union: logits (55.3 KB) during top-k; IoU matrix (14.4 KB) afterwards.
  __shared__ union UMem {
    float logit[N_ANCH];
    float iou[K_TOP][K_TOP];
  } u;
  __shared__ float det[K_TOP][8];
  __shared__ unsigned long long red[TPB / 64];
  __shared__ unsigned long long winner;
  __shared__ int sel_idx[K_TOP];

  const int b = blockIdx.x;
  const int t = threadIdx.x;
  const size_t cbase = (size_t)b * N_ANCH;

  // ---- Phase 1: stage logits into LDS (coalesced) ----
  for (int j = 0; j < PER_T; ++j) {
    int i = (j << 8) | t;
    u.logit[i] = Cls[cbase + i];
  }
  __syncthreads();

  // ---- Phase 2: top-60 by (logit desc, index asc) ----
  // Key: high 32 = monotone-mapped float bits, low 32 = ~index (smaller index wins ties).
  unsigned long long excl = 0ull;   // bit j: element (j*256+t) already extracted
  unsigned long long cand = 0ull;
  for (int j = 0; j < PER_T; ++j) {
    int i = (j << 8) | t;
    unsigned m = __float_as_uint(u.logit[i]);
    m = (m & 0x80000000u) ? ~m : (m | 0x80000000u);
    unsigned long long key = ((unsigned long long)m << 32) | (unsigned)(~i);
    if (key > cand) cand = key;
  }

  for (int p = 0; p < K_TOP; ++p) {
    // wave-level max (butterfly over 64 lanes)
    unsigned long long k = cand;
    #pragma unroll
    for (int s = 1; s < 64; s <<= 1) {
      unsigned long long o = __shfl_xor(k, s, 64);
      if (o > k) k = o;
    }
    if ((t & 63) == 0) red[t >> 6] = k;
    __syncthreads();
    if (t == 0) {
      unsigned long long w = red[0];
      for (int q = 1; q < TPB / 64; ++q) if (red[q] > w) w = red[q];
      winner = w;
      sel_idx[p] = (int)(~(unsigned)(w & 0xffffffffu));
    }
    __syncthreads();
    unsigned long long w = winner;
    int wi = (int)(~(unsigned)(w & 0xffffffffu));
    if ((wi & 255) == t) {
      // I own the winner: remove it and recompute my local max from LDS.
      excl |= 1ull << (wi >> 8);
      cand = 0ull;
      for (int j = 0; j < PER_T; ++j) {
        if ((excl >> j) & 1ull) continue;
        int i = (j << 8) | t;
        unsigned m = __float_as_uint(u.logit[i]);
        m = (m & 0x80000000u) ? ~m : (m | 0x80000000u);
        unsigned long long key = ((unsigned long long)m << 32) | (unsigned)(~i);
        if (key > cand) cand = key;
      }
    }
  }
  __syncthreads();

  // ---- Phase 3: build det[60][8] = [1, score, cz, cy, cx, s0, s1, s2] ----
  if (t < K_TOP) {
    int i = sel_idx[t];
    float lg = u.logit[i];
    float sc = 1.0f / (1.0f + expf(-lg));
    int iz = i / 576;
    int r  = i % 576;
    int iy = r / 24;
    int ix = r - iy * 24;
    size_t bb = (size_t)b * 3 * N_ANCH;
    float o0 = Off[bb + i];
    float o1 = Off[bb + N_ANCH + i];
    float o2 = Off[bb + 2 * N_ANCH + i];
    float s0 = Shp[bb + i];
    float s1 = Shp[bb + N_ANCH + i];
    float s2 = Shp[bb + 2 * N_ANCH + i];
    det[t][0] = 1.0f;
    det[t][1] = sc;
    det[t][2] = ((float)iz + o0) * 4.0f;   // stride = 96/24 = 4
    det[t][3] = ((float)iy + o1) * 4.0f;
    det[t][4] = ((float)ix + o2) * 4.0f;
    det[t][5] = s0;
    det[t][6] = s1;
    det[t][7] = s2;
  }
  __syncthreads();   // det done; u.logit no longer needed past here

  // ---- Phase 4: IoU matrix into the union (overwrites logits) ----
  for (int p = t; p < K_TOP * K_TOP; p += TPB) {
    int ii = p / K_TOP;
    int jj = p - ii * K_TOP;
    float cz1 = det[ii][2], cy1 = det[ii][3], cx1 = det[ii][4];
    float sz1 = det[ii][5], sy1 = det[ii][6], sx1 = det[ii][7];
    float cz2 = det[jj][2], cy2 = det[jj][3], cx2 = det[jj][4];
    float sz2 = det[jj][5], sy2 = det[jj][6], sx2 = det[jj][7];
    float lz1 = cz1 - 0.5f * sz1, hz1 = cz1 + 0.5f * sz1;
    float ly1 = cy1 - 0.5f * sy1, hy1 = cy1 + 0.5f * sy1;
    float lx1 = cx1 - 0.5f * sx1, hx1 = cx1 + 0.5f * sx1;
    float lz2 = cz2 - 0.5f * sz2, hz2 = cz2 + 0.5f * sz2;
    float ly2 = cy2 - 0.5f * sy2, hy2 = cy2 + 0.5f * sy2;
    float lx2 = cx2 - 0.5f * sx2, hx2 = cx2 + 0.5f * sx2;
    float dz = fmaxf(fminf(hz1, hz2) - fmaxf(lz1, lz2), 0.0f);
    float dy = fmaxf(fminf(hy1, hy2) - fmaxf(ly1, ly2), 0.0f);
    float dx = fmaxf(fminf(hx1, hx2) - fmaxf(lx1, lx2), 0.0f);
    float inter = (dz * dy) * dx;
    float v1 = (sz1 * sy1) * sx1;
    float v2 = (sz2 * sy2) * sx2;
    u.iou[ii][jj] = inter / (v1 + v2 - inter);
  }
  __syncthreads();

  // ---- Phase 5: sequential NMS on wave 0 ----
  if (t < 64) {
    const int j = t;
    const bool in = (j < K_TOP);
    float scj = in ? det[j][1] : 0.0f;
    unsigned long long validm = __ballot(in && (scj > 0.15f));
    unsigned long long suppressed = 0ull;
    float* outb = Out + (size_t)b * K_NMS * 8;

    for (int step = 0; step < K_NMS; ++step) {
      unsigned long long avail = validm & ~suppressed;   // wave-uniform
      if (avail) {
        int idx = __builtin_ctzll(avail);
        bool m = in && ((avail >> j) & 1ull) &&
                 ((u.iou[idx][j] > 0.05f) || (j == idx));
        unsigned long long matched = __ballot(m);
        int cnt = __popcll(matched);
        int top_n = cnt < AVG_TOPN ? cnt : AVG_TOPN;
        if (j < 8) {
          float sum = 0.0f;
          unsigned long long mm = matched;
          for (int q = 0; q < top_n; ++q) {
            int bi = __builtin_ctzll(mm);
            mm &= mm - 1ull;
            sum += det[bi][j];
          }
          float r = sum / (float)top_n;   // top_n >= 1 (idx always matches itself)
          if (j == 0) r = 1.0f;
          if (j == 1) r = det[idx][1];
          outb[step * 8 + j] = r;
        }
        suppressed |= matched;
      } else {
        if (j < 8) outb[step * 8 + j] = -1.0f;
      }
    }
  }
}

extern "C" void kernel_launch(void* const* d_in, const int* in_sizes, int n_in,
                              void* d_out, int out_size, void* d_ws, size_t ws_size,
                              hipStream_t stream) {
  const float* Cls = (const float*)d_in[0];
  const float* Shp = (const float*)d_in[1];
  const float* Off = (const float*)d_in[2];
  float* Out = (float*)d_out;
  int B = in_sizes[0] / N_ANCH;   // 256
  detpp_kernel<<<B, TPB, 0, stream>>>(Cls, Shp, Off, Out);
}

// Round 2
// 134.875 us; speedup vs baseline: 2.9979x; 2.9979x over previous
//
#include <hip/hip_runtime.h>
#include <math.h>

#define N_ANCH 13824   // 24*24*24
#define TPB 256
#define K_TOP 60
#define K_NMS 20
#define AVG_TOPN 7

__device__ __forceinline__ unsigned mono_key(float x) {
  unsigned m = __float_as_uint(x);
  return (m & 0x80000000u) ? ~m : (m | 0x80000000u);
}

__global__ __launch_bounds__(TPB)
void detpp_kernel(const float* __restrict__ Cls,
                  const float* __restrict__ Shp,
                  const float* __restrict__ Off,
                  float* __restrict__ Out) {
  // keys (55.3 KB) during select; IoU matrix (14.4 KB) afterwards.
  __shared__ union UMem {
    unsigned int key[N_ANCH];
    float iou[K_TOP][K_TOP];
  } u;
  __shared__ float det[K_TOP][8];
  __shared__ unsigned int hist[256];
  __shared__ unsigned long long cand[64];
  __shared__ unsigned int ccnt;
  __shared__ unsigned int g_prefix;
  __shared__ unsigned int g_r;

  const int b = blockIdx.x;
  const int t = threadIdx.x;
  const int lane = t & 63;

  // ---- Phase 1: load Cls (float4, coalesced), monotone keys -> LDS ----
  const float4* C4 = (const float4*)(Cls + (size_t)b * N_ANCH);  // 3456 float4
  #pragma unroll
  for (int j = 0; j < 13; ++j) {
    int i4 = (j << 8) + t;
    float4 v = C4[i4];
    uint4 k;
    k.x = mono_key(v.x); k.y = mono_key(v.y);
    k.z = mono_key(v.z); k.w = mono_key(v.w);
    ((uint4*)u.key)[i4] = k;
  }
  if (t < 128) {              // remainder: 3456 - 13*256 = 128 float4
    int i4 = 3328 + t;
    float4 v = C4[i4];
    uint4 k;
    k.x = mono_key(v.x); k.y = mono_key(v.y);
    k.z = mono_key(v.z); k.w = mono_key(v.w);
    ((uint4*)u.key)[i4] = k;
  }
  if (t == 0) { ccnt = 0; g_prefix = 0; g_r = K_TOP; }
  __syncthreads();

  // ---- Phase 2: exact radix select of the 60th-largest key (4 x 8-bit MSB-first) ----
  for (int pass = 0; pass < 4; ++pass) {
    const int shift = 24 - 8 * pass;
    hist[t] = 0;
    __syncthreads();
    const unsigned pref = g_prefix;
    const unsigned rr = g_r;
    for (int j = 0; j < 54; ++j) {
      unsigned k = u.key[(j << 8) | t];
      if (((unsigned long long)(k ^ pref) >> (shift + 8)) == 0ull)
        atomicAdd(&hist[(k >> shift) & 0xffu], 1u);
    }
    __syncthreads();
    if (t < 64) {
      unsigned c0 = hist[4 * lane + 0], c1 = hist[4 * lane + 1];
      unsigned c2 = hist[4 * lane + 2], c3 = hist[4 * lane + 3];
      unsigned pre1 = c0, pre2 = c0 + c1, pre3 = pre2 + c2, pre4 = pre3 + c3;
      // inclusive suffix-sum across lanes: S = sum of lane-totals for lanes >= me
      unsigned S = pre4;
      #pragma unroll
      for (int d = 1; d < 64; d <<= 1) {
        unsigned o = __shfl_down(S, d, 64);
        if (lane + d < 64) S += o;
      }
      unsigned pre[5] = {0u, pre1, pre2, pre3, pre4};
      int mybin = -1;
      #pragma unroll
      for (int kk = 3; kk >= 0; --kk) {
        if (mybin < 0 && S - pre[kk] >= rr) mybin = kk;
      }
      unsigned long long m = __ballot(mybin >= 0);
      int hl = 63 - __builtin_clzll(m);
      if (lane == hl) {
        g_prefix = pref | ((unsigned)(4 * lane + mybin) << shift);
        g_r = rr - (S - pre[mybin + 1]);
      }
    }
    __syncthreads();
  }

  // ---- Phase 3: compact candidates (key >= K60), then bitonic sort 64 on wave 0 ----
  const unsigned K60 = g_prefix;
  for (int j = 0; j < 54; ++j) {
    int i = (j << 8) | t;
    unsigned k = u.key[i];
    if (k >= K60) {
      unsigned pos = atomicAdd(&ccnt, 1u);
      if (pos < 64) cand[pos] = ((unsigned long long)k << 32) | (unsigned)(~i);
    }
  }
  __syncthreads();

  if (t < 64) {
    unsigned cnt = ccnt; if (cnt > 64u) cnt = 64u;
    unsigned long long klong = (lane < (int)cnt) ? cand[lane] : 0ull;
    // ascending bitonic sort of ~klong == descending sort of klong (ties: asc index)
    unsigned long long v = ~klong;
    #pragma unroll
    for (int k = 2; k <= 64; k <<= 1) {
      #pragma unroll
      for (int j = k >> 1; j > 0; j >>= 1) {
        unsigned long long o = __shfl_xor(v, j, 64);
        bool i_lower = ((lane & j) == 0);
        bool asc = ((lane & k) == 0);
        bool keep_min = (asc == i_lower);
        bool take = keep_min ? (o < v) : (o > v);
        if (take) v = o;
      }
    }
    klong = ~v;
    if (lane < K_TOP) {
      int i = (int)(~(unsigned)(klong & 0xffffffffull));
      unsigned m = (unsigned)(klong >> 32);
      unsigned bits = (m & 0x80000000u) ? (m & 0x7fffffffu) : ~m;
      float lg = __uint_as_float(bits);
      float sc = 1.0f / (1.0f + expf(-lg));
      int iz = i / 576;
      int r2 = i - iz * 576;
      int iy = r2 / 24;
      int ix = r2 - iy * 24;
      size_t bb = (size_t)b * 3 * N_ANCH;
      float o0 = Off[bb + i];
      float o1 = Off[bb + N_ANCH + i];
      float o2 = Off[bb + 2 * N_ANCH + i];
      float s0 = Shp[bb + i];
      float s1 = Shp[bb + N_ANCH + i];
      float s2 = Shp[bb + 2 * N_ANCH + i];
      det[lane][0] = 1.0f;
      det[lane][1] = sc;
      det[lane][2] = ((float)iz + o0) * 4.0f;   // stride = 96/24 = 4
      det[lane][3] = ((float)iy + o1) * 4.0f;
      det[lane][4] = ((float)ix + o2) * 4.0f;
      det[lane][5] = s0;
      det[lane][6] = s1;
      det[lane][7] = s2;
    }
  }
  __syncthreads();   // det done; u.key no longer needed past here

  // ---- Phase 4: IoU matrix into the union (overwrites keys) ----
  for (int p = t; p < K_TOP * K_TOP; p += TPB) {
    int ii = p / K_TOP;
    int jj = p - ii * K_TOP;
    float cz1 = det[ii][2], cy1 = det[ii][3], cx1 = det[ii][4];
    float sz1 = det[ii][5], sy1 = det[ii][6], sx1 = det[ii][7];
    float cz2 = det[jj][2], cy2 = det[jj][3], cx2 = det[jj][4];
    float sz2 = det[jj][5], sy2 = det[jj][6], sx2 = det[jj][7];
    float lz1 = cz1 - 0.5f * sz1, hz1 = cz1 + 0.5f * sz1;
    float ly1 = cy1 - 0.5f * sy1, hy1 = cy1 + 0.5f * sy1;
    float lx1 = cx1 - 0.5f * sx1, hx1 = cx1 + 0.5f * sx1;
    float lz2 = cz2 - 0.5f * sz2, hz2 = cz2 + 0.5f * sz2;
    float ly2 = cy2 - 0.5f * sy2, hy2 = cy2 + 0.5f * sy2;
    float lx2 = cx2 - 0.5f * sx2, hx2 = cx2 + 0.5f * sx2;
    float dz = fmaxf(fminf(hz1, hz2) - fmaxf(lz1, lz2), 0.0f);
    float dy = fmaxf(fminf(hy1, hy2) - fmaxf(ly1, ly2), 0.0f);
    float dx = fmaxf(fminf(hx1, hx2) - fmaxf(lx1, lx2), 0.0f);
    float inter = (dz * dy) * dx;
    float v1 = (sz1 * sy1) * sx1;
    float v2 = (sz2 * sy2) * sx2;
    u.iou[ii][jj] = inter / (v1 + v2 - inter);
  }
  __syncthreads();

  // ---- Phase 5: sequential NMS on wave 0 ----
  if (t < 64) {
    const int j = t;
    const bool in = (j < K_TOP);
    float scj = in ? det[j][1] : 0.0f;
    unsigned long long validm = __ballot(in && (scj > 0.15f));
    unsigned long long suppressed = 0ull;
    float* outb = Out + (size_t)b * K_NMS * 8;

    for (int step = 0; step < K_NMS; ++step) {
      unsigned long long avail = validm & ~suppressed;   // wave-uniform
      if (avail) {
        int idx = __builtin_ctzll(avail);
        bool m = in && ((avail >> j) & 1ull) &&
                 ((u.iou[idx][j] > 0.05f) || (j == idx));
        unsigned long long matched = __ballot(m);
        int cnt = __popcll(matched);
        int top_n = cnt < AVG_TOPN ? cnt : AVG_TOPN;
        if (j < 8) {
          float sum = 0.0f;
          unsigned long long mm = matched;
          for (int q = 0; q < top_n; ++q) {
            int bi = __builtin_ctzll(mm);
            mm &= mm - 1ull;
            sum += det[bi][j];
          }
          float r = sum / (float)top_n;   // top_n >= 1 (idx always matches itself)
          if (j == 0) r = 1.0f;
          if (j == 1) r = det[idx][1];
          outb[step * 8 + j] = r;
        }
        suppressed |= matched;
      } else {
        if (j < 8) outb[step * 8 + j] = -1.0f;
      }
    }
  }
}

extern "C" void kernel_launch(void* const* d_in, const int* in_sizes, int n_in,
                              void* d_out, int out_size, void* d_ws, size_t ws_size,
                              hipStream_t stream) {
  const float* Cls = (const float*)d_in[0];
  const float* Shp = (const float*)d_in[1];
  const float* Off = (const float*)d_in[2];
  float* Out = (float*)d_out;
  int B = in_sizes[0] / N_ANCH;   // 256
  detpp_kernel<<<B, TPB, 0, stream>>>(Cls, Shp, Off, Out);
}

// Round 3
// 128.896 us; speedup vs baseline: 3.1370x; 1.0464x over previous
//
#include <hip/hip_runtime.h>
#include <math.h>

#define N_ANCH 13824   // 24*24*24
#define TPB 256
#define K_TOP 60
#define K_NMS 20
#define AVG_TOPN 7
#define CAP2 1536
// Conservative prune pivot: z = 2.0 -> float bits 0x40000000 -> mono key 0xC0000000.
// Expected survivors per image for N(0,1) logits: ~314 (needs >= 60, <= CAP2; else exact fallback).
#define PIVOT_KEY 0xC0000000u

__device__ __forceinline__ unsigned mono_key(float x) {
  unsigned m = __float_as_uint(x);
  return (m & 0x80000000u) ? ~m : (m | 0x80000000u);
}

__global__ __launch_bounds__(TPB)
void detpp_kernel(const float* __restrict__ Cls,
                  const float* __restrict__ Shp,
                  const float* __restrict__ Off,
                  float* __restrict__ Out) {
  // cand2 (12.3 KB) during select; IoU matrix (14.4 KB) afterwards.
  __shared__ union UMem {
    unsigned long long cand2[CAP2];
    float iou[K_TOP][K_TOP];
  } u;
  __shared__ float det[K_TOP][8];
  __shared__ unsigned int hist[256];
  __shared__ unsigned long long cand[64];
  __shared__ unsigned int cnt2;
  __shared__ unsigned int ccnt;
  __shared__ unsigned int g_prefix;
  __shared__ unsigned int g_r;

  const int b = blockIdx.x;
  const int t = threadIdx.x;
  const int lane = t & 63;
  const size_t cbase = (size_t)b * N_ANCH;

  if (t == 0) { cnt2 = 0; ccnt = 0; g_prefix = 0u; g_r = K_TOP; }
  hist[t] = 0;
  __syncthreads();

  // ---- Phase 1: stream Cls (float4); prune by pivot; fused histogram + compaction ----
  const float4* C4 = (const float4*)(Cls + cbase);  // 3456 float4
  #pragma unroll
  for (int j = 0; j < 13; ++j) {
    int i4 = (j << 8) + t;
    float4 v = C4[i4];
    int i0 = i4 << 2;
    unsigned kk0 = mono_key(v.x), kk1 = mono_key(v.y);
    unsigned kk2 = mono_key(v.z), kk3 = mono_key(v.w);
    unsigned kks[4] = {kk0, kk1, kk2, kk3};
    #pragma unroll
    for (int q = 0; q < 4; ++q) {
      if (kks[q] > PIVOT_KEY) {
        unsigned pos = atomicAdd(&cnt2, 1u);
        if (pos < CAP2)
          u.cand2[pos] = ((unsigned long long)kks[q] << 32) | (unsigned)(~(i0 + q));
        atomicAdd(&hist[kks[q] >> 24], 1u);
      }
    }
  }
  if (t < 128) {              // remainder: 3456 - 13*256 = 128 float4
    int i4 = 3328 + t;
    float4 v = C4[i4];
    int i0 = i4 << 2;
    unsigned kks[4] = {mono_key(v.x), mono_key(v.y), mono_key(v.z), mono_key(v.w)};
    #pragma unroll
    for (int q = 0; q < 4; ++q) {
      if (kks[q] > PIVOT_KEY) {
        unsigned pos = atomicAdd(&cnt2, 1u);
        if (pos < CAP2)
          u.cand2[pos] = ((unsigned long long)kks[q] << 32) | (unsigned)(~(i0 + q));
        atomicAdd(&hist[kks[q] >> 24], 1u);
      }
    }
  }
  __syncthreads();

  const unsigned total = cnt2;
  const bool fast = (total >= (unsigned)K_TOP) && (total <= (unsigned)CAP2);

  // ---- Phase 2: exact MSB-first radix select of the 60th-largest key ----
  // fast: pass-0 histogram already built (pruned; valid since K60 > PIVOT_KEY when
  //       >= 60 survivors exist); passes 1-3 scan the candidate list.
  // slow (never on bench data): all passes re-scan global Cls — fully general.
  for (int pass = 0; pass < 4; ++pass) {
    const int shift = 24 - 8 * pass;
    const unsigned pref = g_prefix;
    const unsigned rr = g_r;
    if (pass > 0 || !fast) {
      hist[t] = 0;
      __syncthreads();
      if (fast) {
        for (unsigned i = t; i < total; i += TPB) {
          unsigned k = (unsigned)(u.cand2[i] >> 32);
          if (((k ^ pref) >> (shift + 8)) == 0u)   // pass>=1 here, shift+8 <= 24
            atomicAdd(&hist[(k >> shift) & 0xffu], 1u);
        }
      } else {
        for (int j = 0; j < 54; ++j) {
          int i = (j << 8) | t;
          unsigned k = mono_key(Cls[cbase + i]);
          bool match = (pass == 0) ? true : (((k ^ pref) >> (shift + 8)) == 0u);
          if (match) atomicAdd(&hist[(k >> shift) & 0xffu], 1u);
        }
      }
      __syncthreads();
    }
    if (t < 64) {
      unsigned c0 = hist[4 * lane + 0], c1 = hist[4 * lane + 1];
      unsigned c2 = hist[4 * lane + 2], c3 = hist[4 * lane + 3];
      unsigned pre1 = c0, pre2 = c0 + c1, pre3 = pre2 + c2, pre4 = pre3 + c3;
      // inclusive suffix-sum across lanes: S = counts for bins >= 4*lane
      unsigned S = pre4;
      #pragma unroll
      for (int d = 1; d < 64; d <<= 1) {
        unsigned o = __shfl_down(S, d, 64);
        if (lane + d < 64) S += o;
      }
      unsigned pre[5] = {0u, pre1, pre2, pre3, pre4};
      int mybin = -1;
      #pragma unroll
      for (int kk = 3; kk >= 0; --kk) {
        if (mybin < 0 && S - pre[kk] >= rr) mybin = kk;
      }
      unsigned long long m = __ballot(mybin >= 0);
      int hl = 63 - __builtin_clzll(m);
      if (lane == hl) {
        g_prefix = pref | ((unsigned)(4 * lane + mybin) << shift);
        g_r = rr - (S - pre[mybin + 1]);
      }
    }
    __syncthreads();
  }

  // ---- Phase 3: compact keys >= K60 into cand[64], bitonic sort on wave 0 ----
  const unsigned K60 = g_prefix;
  if (fast) {
    for (unsigned i = t; i < total; i += TPB) {
      unsigned long long e = u.cand2[i];
      if ((unsigned)(e >> 32) >= K60) {
        unsigned pos = atomicAdd(&ccnt, 1u);
        if (pos < 64) cand[pos] = e;
      }
    }
  } else {
    for (int j = 0; j < 54; ++j) {
      int i = (j << 8) | t;
      unsigned k = mono_key(Cls[cbase + i]);
      if (k >= K60) {
        unsigned pos = atomicAdd(&ccnt, 1u);
        if (pos < 64) cand[pos] = ((unsigned long long)k << 32) | (unsigned)(~i);
      }
    }
  }
  __syncthreads();

  if (t < 64) {
    unsigned cnt = ccnt; if (cnt > 64u) cnt = 64u;
    unsigned long long klong = (lane < (int)cnt) ? cand[lane] : 0ull;
    // ascending bitonic sort of ~klong == descending sort of klong (ties: asc index)
    unsigned long long v = ~klong;
    #pragma unroll
    for (int k = 2; k <= 64; k <<= 1) {
      #pragma unroll
      for (int j = k >> 1; j > 0; j >>= 1) {
        unsigned long long o = __shfl_xor(v, j, 64);
        bool i_lower = ((lane & j) == 0);
        bool asc = ((lane & k) == 0);
        bool keep_min = (asc == i_lower);
        bool take = keep_min ? (o < v) : (o > v);
        if (take) v = o;
      }
    }
    klong = ~v;
    if (lane < K_TOP) {
      int i = (int)(~(unsigned)(klong & 0xffffffffull));
      unsigned m = (unsigned)(klong >> 32);
      unsigned bits = (m & 0x80000000u) ? (m & 0x7fffffffu) : ~m;
      float lg = __uint_as_float(bits);
      float sc = 1.0f / (1.0f + expf(-lg));
      int iz = i / 576;
      int r2 = i - iz * 576;
      int iy = r2 / 24;
      int ix = r2 - iy * 24;
      size_t bb = (size_t)b * 3 * N_ANCH;
      float o0 = Off[bb + i];
      float o1 = Off[bb + N_ANCH + i];
      float o2 = Off[bb + 2 * N_ANCH + i];
      float s0 = Shp[bb + i];
      float s1 = Shp[bb + N_ANCH + i];
      float s2 = Shp[bb + 2 * N_ANCH + i];
      det[lane][0] = 1.0f;
      det[lane][1] = sc;
      det[lane][2] = ((float)iz + o0) * 4.0f;   // stride = 96/24 = 4
      det[lane][3] = ((float)iy + o1) * 4.0f;
      det[lane][4] = ((float)ix + o2) * 4.0f;
      det[lane][5] = s0;
      det[lane][6] = s1;
      det[lane][7] = s2;
    }
  }
  __syncthreads();   // det done; u.cand2 no longer needed past here

  // ---- Phase 4: IoU matrix into the union (overwrites cand2) ----
  for (int p = t; p < K_TOP * K_TOP; p += TPB) {
    int ii = p / K_TOP;
    int jj = p - ii * K_TOP;
    float cz1 = det[ii][2], cy1 = det[ii][3], cx1 = det[ii][4];
    float sz1 = det[ii][5], sy1 = det[ii][6], sx1 = det[ii][7];
    float cz2 = det[jj][2], cy2 = det[jj][3], cx2 = det[jj][4];
    float sz2 = det[jj][5], sy2 = det[jj][6], sx2 = det[jj][7];
    float lz1 = cz1 - 0.5f * sz1, hz1 = cz1 + 0.5f * sz1;
    float ly1 = cy1 - 0.5f * sy1, hy1 = cy1 + 0.5f * sy1;
    float lx1 = cx1 - 0.5f * sx1, hx1 = cx1 + 0.5f * sx1;
    float lz2 = cz2 - 0.5f * sz2, hz2 = cz2 + 0.5f * sz2;
    float ly2 = cy2 - 0.5f * sy2, hy2 = cy2 + 0.5f * sy2;
    float lx2 = cx2 - 0.5f * sx2, hx2 = cx2 + 0.5f * sx2;
    float dz = fmaxf(fminf(hz1, hz2) - fmaxf(lz1, lz2), 0.0f);
    float dy = fmaxf(fminf(hy1, hy2) - fmaxf(ly1, ly2), 0.0f);
    float dx = fmaxf(fminf(hx1, hx2) - fmaxf(lx1, lx2), 0.0f);
    float inter = (dz * dy) * dx;
    float v1 = (sz1 * sy1) * sx1;
    float v2 = (sz2 * sy2) * sx2;
    u.iou[ii][jj] = inter / (v1 + v2 - inter);
  }
  __syncthreads();

  // ---- Phase 5: sequential NMS on wave 0 ----
  if (t < 64) {
    const int j = t;
    const bool in = (j < K_TOP);
    float scj = in ? det[j][1] : 0.0f;
    unsigned long long validm = __ballot(in && (scj > 0.15f));
    unsigned long long suppressed = 0ull;
    float* outb = Out + (size_t)b * K_NMS * 8;

    for (int step = 0; step < K_NMS; ++step) {
      unsigned long long avail = validm & ~suppressed;   // wave-uniform
      if (avail) {
        int idx = __builtin_ctzll(avail);
        bool m = in && ((avail >> j) & 1ull) &&
                 ((u.iou[idx][j] > 0.05f) || (j == idx));
        unsigned long long matched = __ballot(m);
        int cnt = __popcll(matched);
        int top_n = cnt < AVG_TOPN ? cnt : AVG_TOPN;
        if (j < 8) {
          float sum = 0.0f;
          unsigned long long mm = matched;
          for (int q = 0; q < top_n; ++q) {
            int bi = __builtin_ctzll(mm);
            mm &= mm - 1ull;
            sum += det[bi][j];
          }
          float r = sum / (float)top_n;   // top_n >= 1 (idx always matches itself)
          if (j == 0) r = 1.0f;
          if (j == 1) r = det[idx][1];
          outb[step * 8 + j] = r;
        }
        suppressed |= matched;
      } else {
        if (j < 8) outb[step * 8 + j] = -1.0f;
      }
    }
  }
}

extern "C" void kernel_launch(void* const* d_in, const int* in_sizes, int n_in,
                              void* d_out, int out_size, void* d_ws, size_t ws_size,
                              hipStream_t stream) {
  const float* Cls = (const float*)d_in[0];
  const float* Shp = (const float*)d_in[1];
  const float* Off = (const float*)d_in[2];
  float* Out = (float*)d_out;
  int B = in_sizes[0] / N_ANCH;   // 256
  detpp_kernel<<<B, TPB, 0, stream>>>(Cls, Shp, Off, Out);
}

// Round 4
// 124.780 us; speedup vs baseline: 3.2405x; 1.0330x over previous
//
#include <hip/hip_runtime.h>
#include <math.h>

#define N_ANCH 13824   // 24*24*24
#define TPB 256
#define K_TOP 60
#define K_NMS 20
#define AVG_TOPN 7
#define SLOTS 12       // private candidate slots per thread (overflow -> exact fallback)
// Conservative prune pivot: z = 2.0 -> float bits 0x40000000 -> mono key 0xC0000000.
// ~314 survivors/image expected for N(0,1) logits (needs >=60 and <=12/thread, else fallback).
#define PIVOT_KEY 0xC0000000u

__device__ __forceinline__ unsigned mono_key(float x) {
  unsigned m = __float_as_uint(x);
  return (m & 0x80000000u) ? ~m : (m | 0x80000000u);
}

__global__ __launch_bounds__(TPB)
void detpp_kernel(const float* __restrict__ Cls,
                  const float* __restrict__ Shp,
                  const float* __restrict__ Off,
                  float* __restrict__ Out) {
  __shared__ unsigned long long cand2[TPB * SLOTS];   // 24 KB, private 12-slot regions
  __shared__ float det[K_TOP][8];
  __shared__ unsigned long long Mrow[K_TOP];          // adjacency masks (iou>thr | self)
  __shared__ unsigned int hist[256];
  __shared__ unsigned long long cand[64];
  __shared__ unsigned long long selk[64];
  __shared__ unsigned int ccnt, totcnt, oflow;
  __shared__ unsigned int g_prefix, g_r;

  const int b = blockIdx.x;
  const int t = threadIdx.x;
  const int lane = t & 63;
  const size_t cbase = (size_t)b * N_ANCH;

  if (t == 0) { ccnt = 0; totcnt = 0; oflow = 0; g_prefix = 0u; g_r = K_TOP; }
  if (t < K_TOP) Mrow[t] = 0ull;

  // ---- Phase 1: prefetch all Cls (float4), prune into PRIVATE slots (no atomics) ----
  const float4* C4 = (const float4*)(Cls + cbase);    // 3456 float4
  float4 v[14];
  #pragma unroll
  for (int j = 0; j < 13; ++j) v[j] = C4[(j << 8) + t];
  if (t < 128) v[13] = C4[3328 + t];                  // tail: 3456-13*256=128

  int cnt = 0;
  const int base = t * SLOTS;
  auto process = [&](float4 val, int i0) {
    float a[4] = {val.x, val.y, val.z, val.w};
    #pragma unroll
    for (int q = 0; q < 4; ++q) {
      unsigned k = mono_key(a[q]);
      if (k > PIVOT_KEY) {
        if (cnt < SLOTS)
          cand2[base + cnt] = ((unsigned long long)k << 32) | (unsigned)(~(i0 + q));
        cnt++;
      }
    }
  };
  #pragma unroll
  for (int j = 0; j < 13; ++j) process(v[j], ((j << 8) + t) << 2);
  if (t < 128) process(v[13], (3328 + t) << 2);

  // total survivors + overflow detection (one atomic per wave)
  int wsum = cnt;
  #pragma unroll
  for (int d = 1; d < 64; d <<= 1) wsum += __shfl_xor(wsum, d, 64);
  unsigned long long ofm = __ballot(cnt > SLOTS);
  if (lane == 0) {
    atomicAdd(&totcnt, (unsigned)wsum);
    if (ofm) atomicOr(&oflow, 1u);
  }
  __syncthreads();
  const unsigned total = totcnt;
  const bool fast = (total >= (unsigned)K_TOP) && (oflow == 0u);
  const int myn = cnt < SLOTS ? cnt : SLOTS;

  // ---- Phase 2: exact MSB-first radix select of the 60th-largest key ----
  // fast: scan private slots (valid: K60 > PIVOT when >=60 survivors).
  // slow (never on bench data): re-scan global Cls — fully general.
  #pragma unroll
  for (int pass = 0; pass < 4; ++pass) {
    const int shift = 24 - 8 * pass;
    hist[t] = 0;
    __syncthreads();
    const unsigned pref = g_prefix;
    const unsigned rr = g_r;
    if (fast) {
      for (int kk = 0; kk < myn; ++kk) {
        unsigned k = (unsigned)(cand2[base + kk] >> 32);
        bool match;
        if (pass == 0) match = true;
        else match = (((k ^ pref) >> (shift + 8)) == 0u);
        if (match) atomicAdd(&hist[(k >> shift) & 0xffu], 1u);
      }
    } else {
      for (int j = 0; j < 54; ++j) {
        int i = (j << 8) | t;
        unsigned k = mono_key(Cls[cbase + i]);
        bool match;
        if (pass == 0) match = true;
        else match = (((k ^ pref) >> (shift + 8)) == 0u);
        if (match) atomicAdd(&hist[(k >> shift) & 0xffu], 1u);
      }
    }
    __syncthreads();
    if (t < 64) {
      unsigned c0 = hist[4 * lane + 0], c1 = hist[4 * lane + 1];
      unsigned c2 = hist[4 * lane + 2], c3 = hist[4 * lane + 3];
      unsigned pre1 = c0, pre2 = c0 + c1, pre3 = pre2 + c2, pre4 = pre3 + c3;
      unsigned S = pre4;   // inclusive suffix-sum: counts for bins >= 4*lane
      #pragma unroll
      for (int d = 1; d < 64; d <<= 1) {
        unsigned o = __shfl_down(S, d, 64);
        if (lane + d < 64) S += o;
      }
      unsigned pre[5] = {0u, pre1, pre2, pre3, pre4};
      int mybin = -1;
      #pragma unroll
      for (int kk = 3; kk >= 0; --kk) {
        if (mybin < 0 && S - pre[kk] >= rr) mybin = kk;
      }
      unsigned long long m = __ballot(mybin >= 0);
      int hl = 63 - __builtin_clzll(m);
      if (lane == hl) {
        g_prefix = pref | ((unsigned)(4 * lane + mybin) << shift);
        g_r = rr - (S - pre[mybin + 1]);
      }
    }
    __syncthreads();
  }

  // ---- Phase 3: compact keys >= K60, bitonic sort on wave 0, publish selk ----
  const unsigned K60 = g_prefix;
  if (fast) {
    for (int kk = 0; kk < myn; ++kk) {
      unsigned long long e = cand2[base + kk];
      if ((unsigned)(e >> 32) >= K60) {
        unsigned pos = atomicAdd(&ccnt, 1u);
        if (pos < 64) cand[pos] = e;
      }
    }
  } else {
    for (int j = 0; j < 54; ++j) {
      int i = (j << 8) | t;
      unsigned k = mono_key(Cls[cbase + i]);
      if (k >= K60) {
        unsigned pos = atomicAdd(&ccnt, 1u);
        if (pos < 64) cand[pos] = ((unsigned long long)k << 32) | (unsigned)(~i);
      }
    }
  }
  __syncthreads();

  if (t < 64) {
    unsigned cc = ccnt; if (cc > 64u) cc = 64u;
    unsigned long long klong = (lane < (int)cc) ? cand[lane] : 0ull;
    // ascending bitonic sort of ~klong == descending sort of klong (ties: asc index)
    unsigned long long vv = ~klong;
    #pragma unroll
    for (int k = 2; k <= 64; k <<= 1) {
      #pragma unroll
      for (int j = k >> 1; j > 0; j >>= 1) {
        unsigned long long o = __shfl_xor(vv, j, 64);
        bool i_lower = ((lane & j) == 0);
        bool asc = ((lane & k) == 0);
        bool keep_min = (asc == i_lower);
        bool take = keep_min ? (o < vv) : (o > vv);
        if (take) vv = o;
      }
    }
    selk[lane] = ~vv;
  }
  __syncthreads();

  // ---- Phase 4a: det build with 240 threads (gathers spread over 3 waves) ----
  if (t < 180) {
    int e = t / 3;          // 0..59
    int f = t - 3 * e;      // 0..2
    unsigned long long kl = selk[e];
    int i = (int)(~(unsigned)(kl & 0xffffffffull));
    int iz = i / 576;
    int r2 = i - iz * 576;
    int iy = r2 / 24;
    int ix = r2 - iy * 24;
    int a = (f == 0) ? iz : ((f == 1) ? iy : ix);
    size_t bb = (size_t)b * 3 * N_ANCH + (size_t)f * N_ANCH + (size_t)i;
    float o = Off[bb];
    float s = Shp[bb];
    det[e][2 + f] = ((float)a + o) * 4.0f;   // stride = 96/24 = 4
    det[e][5 + f] = s;
  } else if (t < 240) {
    int e = t - 180;
    unsigned long long kl = selk[e];
    unsigned m = (unsigned)(kl >> 32);
    unsigned bits = (m & 0x80000000u) ? (m & 0x7fffffffu) : ~m;
    float lg = __uint_as_float(bits);
    det[e][0] = 1.0f;
    det[e][1] = 1.0f / (1.0f + expf(-lg));
  }
  __syncthreads();

  // ---- Phase 4b: adjacency masks (identical fp32 divide-then-compare as before) ----
  for (int p = t; p < K_TOP * K_TOP; p += TPB) {
    int ii = p / K_TOP;
    int jj = p - ii * K_TOP;
    float cz1 = det[ii][2], cy1 = det[ii][3], cx1 = det[ii][4];
    float sz1 = det[ii][5], sy1 = det[ii][6], sx1 = det[ii][7];
    float cz2 = det[jj][2], cy2 = det[jj][3], cx2 = det[jj][4];
    float sz2 = det[jj][5], sy2 = det[jj][6], sx2 = det[jj][7];
    float lz1 = cz1 - 0.5f * sz1, hz1 = cz1 + 0.5f * sz1;
    float ly1 = cy1 - 0.5f * sy1, hy1 = cy1 + 0.5f * sy1;
    float lx1 = cx1 - 0.5f * sx1, hx1 = cx1 + 0.5f * sx1;
    float lz2 = cz2 - 0.5f * sz2, hz2 = cz2 + 0.5f * sz2;
    float ly2 = cy2 - 0.5f * sy2, hy2 = cy2 + 0.5f * sy2;
    float lx2 = cx2 - 0.5f * sx2, hx2 = cx2 + 0.5f * sx2;
    float dz = fmaxf(fminf(hz1, hz2) - fmaxf(lz1, lz2), 0.0f);
    float dy = fmaxf(fminf(hy1, hy2) - fmaxf(ly1, ly2), 0.0f);
    float dx = fmaxf(fminf(hx1, hx2) - fmaxf(lx1, lx2), 0.0f);
    float inter = (dz * dy) * dx;
    float v1 = (sz1 * sy1) * sx1;
    float v2 = (sz2 * sy2) * sx2;
    float iouv = inter / (v1 + v2 - inter);
    if ((iouv > 0.05f) || (jj == ii)) atomicOr(&Mrow[ii], 1ull << jj);
  }
  __syncthreads();

  // ---- Phase 5: NMS on wave 0 — scalar chain + (q,c) tree-sum payload ----
  if (t < 64) {
    const bool in = (lane < K_TOP);
    float myscore = in ? det[lane][1] : 0.0f;
    unsigned long long M = in ? Mrow[lane] : 0ull;
    unsigned long long validm = __ballot(in && (myscore > 0.15f));
    unsigned long long suppressed = 0ull;
    float* outb = Out + (size_t)b * K_NMS * 8;
    const int q = lane >> 3, c = lane & 7;

    #pragma unroll
    for (int step = 0; step < K_NMS; ++step) {
      unsigned long long avail = validm & ~suppressed;
      const bool any = (avail != 0ull);
      int idx = any ? (int)__builtin_ctzll(avail) : 0;
      unsigned mlo = (unsigned)__builtin_amdgcn_readlane((int)(unsigned)(M & 0xffffffffull), idx);
      unsigned mhi = (unsigned)__builtin_amdgcn_readlane((int)(unsigned)(M >> 32), idx);
      unsigned long long matched = any ? (avail & (((unsigned long long)mhi << 32) | mlo)) : 0ull;
      int cm = __popcll(matched);
      int top_n = cm < AVG_TOPN ? cm : AVG_TOPN;
      // lane (q,c) reads det[b_q][c]; b_q = q-th set bit of matched (ascending)
      int myb = 0;
      { unsigned long long m2 = matched;
        #pragma unroll
        for (int z = 0; z < 8; ++z) {
          int bz = m2 ? (int)__builtin_ctzll(m2) : 0;
          if (z == q) myb = bz;
          m2 &= m2 - 1ull;
        } }
      float vv = (q < top_n) ? det[myb][c] : 0.0f;
      vv += __shfl_xor(vv, 8, 64);
      vv += __shfl_xor(vv, 16, 64);
      vv += __shfl_xor(vv, 32, 64);
      float sidx = __uint_as_float((unsigned)__builtin_amdgcn_readlane((int)__float_as_uint(myscore), idx));
      float r = vv / (float)(top_n > 0 ? top_n : 1);
      if (lane < 8) {
        float o = r;
        if (lane == 0) o = 1.0f;
        if (lane == 1) o = sidx;
        if (!any) o = -1.0f;
        outb[step * 8 + lane] = o;
      }
      suppressed |= matched;
    }
  }
}

extern "C" void kernel_launch(void* const* d_in, const int* in_sizes, int n_in,
                              void* d_out, int out_size, void* d_ws, size_t ws_size,
                              hipStream_t stream) {
  const float* Cls = (const float*)d_in[0];
  const float* Shp = (const float*)d_in[1];
  const float* Off = (const float*)d_in[2];
  float* Out = (float*)d_out;
  int B = in_sizes[0] / N_ANCH;   // 256
  detpp_kernel<<<B, TPB, 0, stream>>>(Cls, Shp, Off, Out);
}

// Round 5
// 123.163 us; speedup vs baseline: 3.2830x; 1.0131x over previous
//
#include <hip/hip_runtime.h>
#include <math.h>

#define N_ANCH 13824   // 24*24*24
#define TPB 256
#define K_TOP 60
#define K_NMS 20
#define AVG_TOPN 7
#define SLOTS 12       // private candidate slots per thread (overflow -> exact fallback)
// Conservative prune pivot: z = 2.25 -> float bits 0x40100000 -> mono key 0xC0100000.
// ~169 survivors/image expected for N(0,1) logits (needs >=60, no thread-overflow; else exact fallback).
#define PIVOT_KEY 0xC0100000u

__device__ __forceinline__ unsigned mono_key(float x) {
  unsigned m = __float_as_uint(x);
  return (m & 0x80000000u) ? ~m : (m | 0x80000000u);
}

__global__ __launch_bounds__(TPB)
void detpp_kernel(const float* __restrict__ Cls,
                  const float* __restrict__ Shp,
                  const float* __restrict__ Off,
                  float* __restrict__ Out) {
  __shared__ unsigned long long cand2[TPB * SLOTS];   // 24 KB, private 12-slot regions
  __shared__ float det[K_TOP][9];                     // stride 9: bank-conflict-free gathers
  __shared__ unsigned long long Mrow[K_TOP];          // adjacency masks (self-bit preset)
  __shared__ unsigned int hist[4][256];               // one pre-zeroed histogram per radix pass
  __shared__ unsigned long long cand[64];
  __shared__ unsigned long long selk[64];
  __shared__ unsigned int ccnt, totcnt, oflow;
  __shared__ unsigned int g_prefix, g_r;

  const int b = blockIdx.x;
  const int t = threadIdx.x;
  const int lane = t & 63;
  const size_t cbase = (size_t)b * N_ANCH;

  if (t == 0) { ccnt = 0; totcnt = 0; oflow = 0; g_prefix = 0u; g_r = K_TOP; }
  if (t < K_TOP) Mrow[t] = 1ull << t;   // diagonal: (ar == idx) term
  hist[0][t] = 0; hist[1][t] = 0; hist[2][t] = 0; hist[3][t] = 0;

  // ---- Phase 1: prefetch all Cls (float4), prune into PRIVATE slots (no atomics) ----
  const float4* C4 = (const float4*)(Cls + cbase);    // 3456 float4
  float4 v[14];
  #pragma unroll
  for (int j = 0; j < 13; ++j) v[j] = C4[(j << 8) + t];
  if (t < 128) v[13] = C4[3328 + t];                  // tail: 3456-13*256=128

  int cnt = 0;
  const int base = t * SLOTS;
  auto process = [&](float4 val, int i0) {
    float a[4] = {val.x, val.y, val.z, val.w};
    #pragma unroll
    for (int q = 0; q < 4; ++q) {
      unsigned k = mono_key(a[q]);
      if (k > PIVOT_KEY) {
        if (cnt < SLOTS)
          cand2[base + cnt] = ((unsigned long long)k << 32) | (unsigned)(~(i0 + q));
        cnt++;
      }
    }
  };
  #pragma unroll
  for (int j = 0; j < 13; ++j) process(v[j], ((j << 8) + t) << 2);
  if (t < 128) process(v[13], (3328 + t) << 2);

  // total survivors + overflow detection (one atomic per wave)
  int wsum = cnt;
  #pragma unroll
  for (int d = 1; d < 64; d <<= 1) wsum += __shfl_xor(wsum, d, 64);
  unsigned long long ofm = __ballot(cnt > SLOTS);
  if (lane == 0) {
    atomicAdd(&totcnt, (unsigned)wsum);
    if (ofm) atomicOr(&oflow, 1u);
  }
  __syncthreads();
  const unsigned total = totcnt;
  const bool fast = (total >= (unsigned)K_TOP) && (oflow == 0u);
  const int myn = cnt < SLOTS ? cnt : SLOTS;

  // ---- Phase 2: exact MSB-first radix select of the 60th-largest key ----
  // fast: scan private slots (valid: K60 > PIVOT when >=60 survivors).
  // slow (never on bench data): re-scan global Cls — fully general.
  #pragma unroll
  for (int pass = 0; pass < 4; ++pass) {
    const int shift = 24 - 8 * pass;
    const unsigned pref = g_prefix;
    const unsigned rr = g_r;
    if (fast) {
      for (int kk = 0; kk < myn; ++kk) {
        unsigned k = (unsigned)(cand2[base + kk] >> 32);
        bool match;
        if (pass == 0) match = true;
        else match = (((k ^ pref) >> (shift + 8)) == 0u);
        if (match) atomicAdd(&hist[pass][(k >> shift) & 0xffu], 1u);
      }
    } else {
      for (int j = 0; j < 54; ++j) {
        int i = (j << 8) | t;
        unsigned k = mono_key(Cls[cbase + i]);
        bool match;
        if (pass == 0) match = true;
        else match = (((k ^ pref) >> (shift + 8)) == 0u);
        if (match) atomicAdd(&hist[pass][(k >> shift) & 0xffu], 1u);
      }
    }
    __syncthreads();
    if (t < 64) {
      unsigned c0 = hist[pass][4 * lane + 0], c1 = hist[pass][4 * lane + 1];
      unsigned c2 = hist[pass][4 * lane + 2], c3 = hist[pass][4 * lane + 3];
      unsigned pre1 = c0, pre2 = c0 + c1, pre3 = pre2 + c2, pre4 = pre3 + c3;
      unsigned S = pre4;   // inclusive suffix-sum: counts for bins >= 4*lane
      #pragma unroll
      for (int d = 1; d < 64; d <<= 1) {
        unsigned o = __shfl_down(S, d, 64);
        if (lane + d < 64) S += o;
      }
      unsigned pre[5] = {0u, pre1, pre2, pre3, pre4};
      int mybin = -1;
      #pragma unroll
      for (int kk = 3; kk >= 0; --kk) {
        if (mybin < 0 && S - pre[kk] >= rr) mybin = kk;
      }
      unsigned long long m = __ballot(mybin >= 0);
      int hl = 63 - __builtin_clzll(m);
      if (lane == hl) {
        g_prefix = pref | ((unsigned)(4 * lane + mybin) << shift);
        g_r = rr - (S - pre[mybin + 1]);
      }
    }
    __syncthreads();
  }

  // ---- Phase 3: compact keys >= K60, bitonic sort on wave 0, publish selk ----
  const unsigned K60 = g_prefix;
  if (fast) {
    for (int kk = 0; kk < myn; ++kk) {
      unsigned long long e = cand2[base + kk];
      if ((unsigned)(e >> 32) >= K60) {
        unsigned pos = atomicAdd(&ccnt, 1u);
        if (pos < 64) cand[pos] = e;
      }
    }
  } else {
    for (int j = 0; j < 54; ++j) {
      int i = (j << 8) | t;
      unsigned k = mono_key(Cls[cbase + i]);
      if (k >= K60) {
        unsigned pos = atomicAdd(&ccnt, 1u);
        if (pos < 64) cand[pos] = ((unsigned long long)k << 32) | (unsigned)(~i);
      }
    }
  }
  __syncthreads();

  if (t < 64) {
    unsigned cc = ccnt; if (cc > 64u) cc = 64u;
    unsigned long long klong = (lane < (int)cc) ? cand[lane] : 0ull;
    // ascending bitonic sort of ~klong == descending sort of klong (ties: asc index)
    unsigned long long vv = ~klong;
    #pragma unroll
    for (int k = 2; k <= 64; k <<= 1) {
      #pragma unroll
      for (int j = k >> 1; j > 0; j >>= 1) {
        unsigned long long o = __shfl_xor(vv, j, 64);
        bool i_lower = ((lane & j) == 0);
        bool asc = ((lane & k) == 0);
        bool keep_min = (asc == i_lower);
        bool take = keep_min ? (o < vv) : (o > vv);
        if (take) vv = o;
      }
    }
    selk[lane] = ~vv;
  }
  __syncthreads();

  // ---- Phase 4a: det build with 240 threads (gathers spread over 3 waves) ----
  if (t < 180) {
    int e = t / 3;          // 0..59
    int f = t - 3 * e;      // 0..2
    unsigned long long kl = selk[e];
    int i = (int)(~(unsigned)(kl & 0xffffffffull));
    int iz = i / 576;
    int r2 = i - iz * 576;
    int iy = r2 / 24;
    int ix = r2 - iy * 24;
    int a = (f == 0) ? iz : ((f == 1) ? iy : ix);
    size_t bb = (size_t)b * 3 * N_ANCH + (size_t)f * N_ANCH + (size_t)i;
    float o = Off[bb];
    float s = Shp[bb];
    det[e][2 + f] = ((float)a + o) * 4.0f;   // stride = 96/24 = 4
    det[e][5 + f] = s;
  } else if (t < 240) {
    int e = t - 180;
    unsigned long long kl = selk[e];
    unsigned m = (unsigned)(kl >> 32);
    unsigned bits = (m & 0x80000000u) ? (m & 0x7fffffffu) : ~m;
    float lg = __uint_as_float(bits);
    det[e][0] = 1.0f;
    det[e][1] = 1.0f / (1.0f + expf(-lg));
  }
  __syncthreads();

  // ---- Phase 4b: adjacency masks, SYMMETRIC (1800 round-robin pairs, both bits) ----
  // Pair set: (ii, (ii+1+k)%60), k in [0,30). d=30 pairs occur twice -> idempotent OR.
  // IoU expression is bitwise symmetric, so one evaluation serves both directions.
  for (int p = t; p < 1800; p += TPB) {
    int ii = p / 30;
    int k  = p - ii * 30;
    int jj = ii + 1 + k; if (jj >= 60) jj -= 60;
    float cz1 = det[ii][2], cy1 = det[ii][3], cx1 = det[ii][4];
    float sz1 = det[ii][5], sy1 = det[ii][6], sx1 = det[ii][7];
    float cz2 = det[jj][2], cy2 = det[jj][3], cx2 = det[jj][4];
    float sz2 = det[jj][5], sy2 = det[jj][6], sx2 = det[jj][7];
    float lz1 = cz1 - 0.5f * sz1, hz1 = cz1 + 0.5f * sz1;
    float ly1 = cy1 - 0.5f * sy1, hy1 = cy1 + 0.5f * sy1;
    float lx1 = cx1 - 0.5f * sx1, hx1 = cx1 + 0.5f * sx1;
    float lz2 = cz2 - 0.5f * sz2, hz2 = cz2 + 0.5f * sz2;
    float ly2 = cy2 - 0.5f * sy2, hy2 = cy2 + 0.5f * sy2;
    float lx2 = cx2 - 0.5f * sx2, hx2 = cx2 + 0.5f * sx2;
    float dz = fmaxf(fminf(hz1, hz2) - fmaxf(lz1, lz2), 0.0f);
    float dy = fmaxf(fminf(hy1, hy2) - fmaxf(ly1, ly2), 0.0f);
    float dx = fmaxf(fminf(hx1, hx2) - fmaxf(lx1, lx2), 0.0f);
    float inter = (dz * dy) * dx;
    float v1 = (sz1 * sy1) * sx1;
    float v2 = (sz2 * sy2) * sx2;
    float iouv = inter / (v1 + v2 - inter);
    if (iouv > 0.05f) {
      atomicOr(&Mrow[ii], 1ull << jj);
      atomicOr(&Mrow[jj], 1ull << ii);
    }
  }
  __syncthreads();

  // ---- Phase 5: NMS on wave 0 — scalar chain + (q,c) tree-sum payload ----
  if (t < 64) {
    const bool in = (lane < K_TOP);
    float myscore = in ? det[lane][1] : 0.0f;
    unsigned long long M = in ? Mrow[lane] : 0ull;
    unsigned long long validm = __ballot(in && (myscore > 0.15f));
    unsigned long long suppressed = 0ull;
    float* outb = Out + (size_t)b * K_NMS * 8;
    const int q = lane >> 3, c = lane & 7;

    #pragma unroll
    for (int step = 0; step < K_NMS; ++step) {
      unsigned long long avail = validm & ~suppressed;
      const bool any = (avail != 0ull);
      int idx = any ? (int)__builtin_ctzll(avail) : 0;
      unsigned mlo = (unsigned)__builtin_amdgcn_readlane((int)(unsigned)(M & 0xffffffffull), idx);
      unsigned mhi = (unsigned)__builtin_amdgcn_readlane((int)(unsigned)(M >> 32), idx);
      unsigned long long matched = any ? (avail & (((unsigned long long)mhi << 32) | mlo)) : 0ull;
      int cm = __popcll(matched);
      int top_n = cm < AVG_TOPN ? cm : AVG_TOPN;
      // lane (q,c) reads det[b_q][c]; b_q = q-th set bit of matched (ascending)
      int myb = 0;
      { unsigned long long m2 = matched;
        #pragma unroll
        for (int z = 0; z < 8; ++z) {
          int bz = m2 ? (int)__builtin_ctzll(m2) : 0;
          if (z == q) myb = bz;
          m2 &= m2 - 1ull;
        } }
      float vv = (q < top_n) ? det[myb][c] : 0.0f;
      vv += __shfl_xor(vv, 8, 64);
      vv += __shfl_xor(vv, 16, 64);
      vv += __shfl_xor(vv, 32, 64);
      float sidx = __uint_as_float((unsigned)__builtin_amdgcn_readlane((int)__float_as_uint(myscore), idx));
      float r = vv / (float)(top_n > 0 ? top_n : 1);
      if (lane < 8) {
        float o = r;
        if (lane == 0) o = 1.0f;
        if (lane == 1) o = sidx;
        if (!any) o = -1.0f;
        outb[step * 8 + lane] = o;
      }
      suppressed |= matched;
    }
  }
}

extern "C" void kernel_launch(void* const* d_in, const int* in_sizes, int n_in,
                              void* d_out, int out_size, void* d_ws, size_t ws_size,
                              hipStream_t stream) {
  const float* Cls = (const float*)d_in[0];
  const float* Shp = (const float*)d_in[1];
  const float* Off = (const float*)d_in[2];
  float* Out = (float*)d_out;
  int B = in_sizes[0] / N_ANCH;   // 256
  detpp_kernel<<<B, TPB, 0, stream>>>(Cls, Shp, Off, Out);
}

// Round 6
// 120.705 us; speedup vs baseline: 3.3498x; 1.0204x over previous
//
#include <hip/hip_runtime.h>
#include <math.h>

#define N_ANCH 13824   // 24*24*24
#define TPB 1024
#define K_TOP 60
#define K_NMS 20
#define AVG_TOPN 7
#define SLOTS 8        // private candidate slots per thread (overflow -> exact fallback)
// Conservative prune pivot: z = 2.25 -> float bits 0x40100000 -> mono key 0xC0100000.
// ~169 survivors/image expected for N(0,1) logits (needs >=60, no thread-overflow; else exact fallback).
#define PIVOT_KEY 0xC0100000u

__device__ __forceinline__ unsigned mono_key(float x) {
  unsigned m = __float_as_uint(x);
  return (m & 0x80000000u) ? ~m : (m | 0x80000000u);
}

__global__ __launch_bounds__(TPB)
void detpp_kernel(const float* __restrict__ Cls,
                  const float* __restrict__ Shp,
                  const float* __restrict__ Off,
                  float* __restrict__ Out) {
  __shared__ unsigned long long cand2[TPB * SLOTS];   // 64 KB, private 8-slot regions
  __shared__ float det[K_TOP][9];                     // stride 9: bank-conflict-free gathers
  __shared__ unsigned long long Mrow[K_TOP];          // adjacency masks (self-bit preset)
  __shared__ unsigned int hist[4][256];               // one pre-zeroed histogram per radix pass
  __shared__ unsigned long long cand[64];
  __shared__ unsigned long long selk[64];
  __shared__ unsigned int ccnt, totcnt, oflow;
  __shared__ unsigned int g_prefix, g_r;

  const int b = blockIdx.x;
  const int t = threadIdx.x;
  const int lane = t & 63;
  const size_t cbase = (size_t)b * N_ANCH;

  if (t == 0) { ccnt = 0; totcnt = 0; oflow = 0; g_prefix = 0u; g_r = K_TOP; }
  if (t < K_TOP) Mrow[t] = 1ull << t;   // diagonal: (ar == idx) term
  if (t < 256) { hist[0][t] = 0; hist[1][t] = 0; hist[2][t] = 0; hist[3][t] = 0; }

  // ---- Phase 1: prefetch Cls (float4), prune into PRIVATE slots (no atomics) ----
  // 3456 float4 over 1024 threads: 3 full rounds + 384 tail.
  const float4* C4 = (const float4*)(Cls + cbase);
  float4 v[4];
  #pragma unroll
  for (int j = 0; j < 3; ++j) v[j] = C4[(j << 10) + t];
  if (t < 384) v[3] = C4[3072 + t];

  int cnt = 0;
  const int base = t * SLOTS;
  auto process = [&](float4 val, int i0) {
    float a[4] = {val.x, val.y, val.z, val.w};
    #pragma unroll
    for (int q = 0; q < 4; ++q) {
      unsigned k = mono_key(a[q]);
      if (k > PIVOT_KEY) {
        if (cnt < SLOTS)
          cand2[base + cnt] = ((unsigned long long)k << 32) | (unsigned)(~(i0 + q));
        cnt++;
      }
    }
  };
  #pragma unroll
  for (int j = 0; j < 3; ++j) process(v[j], ((j << 10) + t) << 2);
  if (t < 384) process(v[3], (3072 + t) << 2);

  // total survivors + overflow detection (one atomic per wave)
  int wsum = cnt;
  #pragma unroll
  for (int d = 1; d < 64; d <<= 1) wsum += __shfl_xor(wsum, d, 64);
  unsigned long long ofm = __ballot(cnt > SLOTS);
  if (lane == 0) {
    atomicAdd(&totcnt, (unsigned)wsum);
    if (ofm) atomicOr(&oflow, 1u);
  }
  __syncthreads();
  const unsigned total = totcnt;
  const bool fast = (total >= (unsigned)K_TOP) && (oflow == 0u);
  const int myn = cnt < SLOTS ? cnt : SLOTS;

  // ---- Phase 2: exact MSB-first radix select of the 60th-largest key ----
  // fast: scan private slots (valid: K60 > PIVOT when >=60 survivors).
  // slow (never on bench data): re-scan global Cls — fully general.
  #pragma unroll
  for (int pass = 0; pass < 4; ++pass) {
    const int shift = 24 - 8 * pass;
    const unsigned pref = g_prefix;
    const unsigned rr = g_r;
    if (fast) {
      for (int kk = 0; kk < myn; ++kk) {
        unsigned k = (unsigned)(cand2[base + kk] >> 32);
        bool match;
        if (pass == 0) match = true;
        else match = (((k ^ pref) >> (shift + 8)) == 0u);
        if (match) atomicAdd(&hist[pass][(k >> shift) & 0xffu], 1u);
      }
    } else {
      // 13824 = 13*1024 + 512
      for (int j = 0; j < 13; ++j) {
        int i = (j << 10) + t;
        unsigned k = mono_key(Cls[cbase + i]);
        bool match;
        if (pass == 0) match = true;
        else match = (((k ^ pref) >> (shift + 8)) == 0u);
        if (match) atomicAdd(&hist[pass][(k >> shift) & 0xffu], 1u);
      }
      if (t < 512) {
        int i = 13312 + t;
        unsigned k = mono_key(Cls[cbase + i]);
        bool match;
        if (pass == 0) match = true;
        else match = (((k ^ pref) >> (shift + 8)) == 0u);
        if (match) atomicAdd(&hist[pass][(k >> shift) & 0xffu], 1u);
      }
    }
    __syncthreads();
    if (t < 64) {
      unsigned c0 = hist[pass][4 * lane + 0], c1 = hist[pass][4 * lane + 1];
      unsigned c2 = hist[pass][4 * lane + 2], c3 = hist[pass][4 * lane + 3];
      unsigned pre1 = c0, pre2 = c0 + c1, pre3 = pre2 + c2, pre4 = pre3 + c3;
      unsigned S = pre4;   // inclusive suffix-sum: counts for bins >= 4*lane
      #pragma unroll
      for (int d = 1; d < 64; d <<= 1) {
        unsigned o = __shfl_down(S, d, 64);
        if (lane + d < 64) S += o;
      }
      unsigned pre[5] = {0u, pre1, pre2, pre3, pre4};
      int mybin = -1;
      #pragma unroll
      for (int kk = 3; kk >= 0; --kk) {
        if (mybin < 0 && S - pre[kk] >= rr) mybin = kk;
      }
      unsigned long long m = __ballot(mybin >= 0);
      int hl = 63 - __builtin_clzll(m);
      if (lane == hl) {
        g_prefix = pref | ((unsigned)(4 * lane + mybin) << shift);
        g_r = rr - (S - pre[mybin + 1]);
      }
    }
    __syncthreads();
  }

  // ---- Phase 3: compact keys >= K60, bitonic sort on wave 0, publish selk ----
  const unsigned K60 = g_prefix;
  if (fast) {
    for (int kk = 0; kk < myn; ++kk) {
      unsigned long long e = cand2[base + kk];
      if ((unsigned)(e >> 32) >= K60) {
        unsigned pos = atomicAdd(&ccnt, 1u);
        if (pos < 64) cand[pos] = e;
      }
    }
  } else {
    for (int j = 0; j < 13; ++j) {
      int i = (j << 10) + t;
      unsigned k = mono_key(Cls[cbase + i]);
      if (k >= K60) {
        unsigned pos = atomicAdd(&ccnt, 1u);
        if (pos < 64) cand[pos] = ((unsigned long long)k << 32) | (unsigned)(~i);
      }
    }
    if (t < 512) {
      int i = 13312 + t;
      unsigned k = mono_key(Cls[cbase + i]);
      if (k >= K60) {
        unsigned pos = atomicAdd(&ccnt, 1u);
        if (pos < 64) cand[pos] = ((unsigned long long)k << 32) | (unsigned)(~i);
      }
    }
  }
  __syncthreads();

  if (t < 64) {
    unsigned cc = ccnt; if (cc > 64u) cc = 64u;
    unsigned long long klong = (lane < (int)cc) ? cand[lane] : 0ull;
    // ascending bitonic sort of ~klong == descending sort of klong (ties: asc index)
    unsigned long long vv = ~klong;
    #pragma unroll
    for (int k = 2; k <= 64; k <<= 1) {
      #pragma unroll
      for (int j = k >> 1; j > 0; j >>= 1) {
        unsigned long long o = __shfl_xor(vv, j, 64);
        bool i_lower = ((lane & j) == 0);
        bool asc = ((lane & k) == 0);
        bool keep_min = (asc == i_lower);
        bool take = keep_min ? (o < vv) : (o > vv);
        if (take) vv = o;
      }
    }
    selk[lane] = ~vv;
  }
  __syncthreads();

  // ---- Phase 4a: det build with 240 threads (gathers spread over waves) ----
  if (t < 180) {
    int e = t / 3;          // 0..59
    int f = t - 3 * e;      // 0..2
    unsigned long long kl = selk[e];
    int i = (int)(~(unsigned)(kl & 0xffffffffull));
    int iz = i / 576;
    int r2 = i - iz * 576;
    int iy = r2 / 24;
    int ix = r2 - iy * 24;
    int a = (f == 0) ? iz : ((f == 1) ? iy : ix);
    size_t bb = (size_t)b * 3 * N_ANCH + (size_t)f * N_ANCH + (size_t)i;
    float o = Off[bb];
    float s = Shp[bb];
    det[e][2 + f] = ((float)a + o) * 4.0f;   // stride = 96/24 = 4
    det[e][5 + f] = s;
  } else if (t < 240) {
    int e = t - 180;
    unsigned long long kl = selk[e];
    unsigned m = (unsigned)(kl >> 32);
    unsigned bits = (m & 0x80000000u) ? (m & 0x7fffffffu) : ~m;
    float lg = __uint_as_float(bits);
    det[e][0] = 1.0f;
    det[e][1] = 1.0f / (1.0f + expf(-lg));
  }
  __syncthreads();

  // ---- Phase 4b: adjacency masks, SYMMETRIC (1800 round-robin pairs, both bits) ----
  // Pair set: (ii, (ii+1+k)%60), k in [0,30). d=30 pairs occur twice -> idempotent OR.
  // IoU expression is bitwise symmetric, so one evaluation serves both directions.
  for (int p = t; p < 1800; p += TPB) {
    int ii = p / 30;
    int k  = p - ii * 30;
    int jj = ii + 1 + k; if (jj >= 60) jj -= 60;
    float cz1 = det[ii][2], cy1 = det[ii][3], cx1 = det[ii][4];
    float sz1 = det[ii][5], sy1 = det[ii][6], sx1 = det[ii][7];
    float cz2 = det[jj][2], cy2 = det[jj][3], cx2 = det[jj][4];
    float sz2 = det[jj][5], sy2 = det[jj][6], sx2 = det[jj][7];
    float lz1 = cz1 - 0.5f * sz1, hz1 = cz1 + 0.5f * sz1;
    float ly1 = cy1 - 0.5f * sy1, hy1 = cy1 + 0.5f * sy1;
    float lx1 = cx1 - 0.5f * sx1, hx1 = cx1 + 0.5f * sx1;
    float lz2 = cz2 - 0.5f * sz2, hz2 = cz2 + 0.5f * sz2;
    float ly2 = cy2 - 0.5f * sy2, hy2 = cy2 + 0.5f * sy2;
    float lx2 = cx2 - 0.5f * sx2, hx2 = cx2 + 0.5f * sx2;
    float dz = fmaxf(fminf(hz1, hz2) - fmaxf(lz1, lz2), 0.0f);
    float dy = fmaxf(fminf(hy1, hy2) - fmaxf(ly1, ly2), 0.0f);
    float dx = fmaxf(fminf(hx1, hx2) - fmaxf(lx1, lx2), 0.0f);
    float inter = (dz * dy) * dx;
    float v1 = (sz1 * sy1) * sx1;
    float v2 = (sz2 * sy2) * sx2;
    float iouv = inter / (v1 + v2 - inter);
    if (iouv > 0.05f) {
      atomicOr(&Mrow[ii], 1ull << jj);
      atomicOr(&Mrow[jj], 1ull << ii);
    }
  }
  __syncthreads();

  // ---- Phase 5: NMS on wave 0 — scalar chain + (q,c) tree-sum payload ----
  if (t < 64) {
    const bool in = (lane < K_TOP);
    float myscore = in ? det[lane][1] : 0.0f;
    unsigned long long M = in ? Mrow[lane] : 0ull;
    unsigned long long validm = __ballot(in && (myscore > 0.15f));
    unsigned long long suppressed = 0ull;
    float* outb = Out + (size_t)b * K_NMS * 8;
    const int q = lane >> 3, c = lane & 7;

    #pragma unroll
    for (int step = 0; step < K_NMS; ++step) {
      unsigned long long avail = validm & ~suppressed;
      const bool any = (avail != 0ull);
      int idx = any ? (int)__builtin_ctzll(avail) : 0;
      unsigned mlo = (unsigned)__builtin_amdgcn_readlane((int)(unsigned)(M & 0xffffffffull), idx);
      unsigned mhi = (unsigned)__builtin_amdgcn_readlane((int)(unsigned)(M >> 32), idx);
      unsigned long long matched = any ? (avail & (((unsigned long long)mhi << 32) | mlo)) : 0ull;
      int cm = __popcll(matched);
      int top_n = cm < AVG_TOPN ? cm : AVG_TOPN;
      // lane (q,c) reads det[b_q][c]; b_q = q-th set bit of matched (ascending)
      int myb = 0;
      { unsigned long long m2 = matched;
        #pragma unroll
        for (int z = 0; z < 8; ++z) {
          int bz = m2 ? (int)__builtin_ctzll(m2) : 0;
          if (z == q) myb = bz;
          m2 &= m2 - 1ull;
        } }
      float vv = (q < top_n) ? det[myb][c] : 0.0f;
      vv += __shfl_xor(vv, 8, 64);
      vv += __shfl_xor(vv, 16, 64);
      vv += __shfl_xor(vv, 32, 64);
      float sidx = __uint_as_float((unsigned)__builtin_amdgcn_readlane((int)__float_as_uint(myscore), idx));
      float r = vv / (float)(top_n > 0 ? top_n : 1);
      if (lane < 8) {
        float o = r;
        if (lane == 0) o = 1.0f;
        if (lane == 1) o = sidx;
        if (!any) o = -1.0f;
        outb[step * 8 + lane] = o;
      }
      suppressed |= matched;
    }
  }
}

extern "C" void kernel_launch(void* const* d_in, const int* in_sizes, int n_in,
                              void* d_out, int out_size, void* d_ws, size_t ws_size,
                              hipStream_t stream) {
  const float* Cls = (const float*)d_in[0];
  const float* Shp = (const float*)d_in[1];
  const float* Off = (const float*)d_in[2];
  float* Out = (float*)d_out;
  int B = in_sizes[0] / N_ANCH;   // 256
  detpp_kernel<<<B, TPB, 0, stream>>>(Cls, Shp, Off, Out);
}

// Round 7
// 117.798 us; speedup vs baseline: 3.4325x; 1.0247x over previous
//
#include <hip/hip_runtime.h>
#include <math.h>

#define N_ANCH 13824   // 24*24*24
#define TPB 1024
#define K_TOP 60
#define K_NMS 20
#define AVG_TOPN 7
#define CAP 2048       // survivor list capacity (16 KB LDS); overflow -> exact fallback
// Conservative prune pivot: z = 2.25 -> float bits 0x40100000 -> mono key 0xC0100000.
// ~169 +/- 13 survivors/image for N(0,1) logits; needs >=60 and <=CAP, else exact fallback.
#define PIVOT_KEY 0xC0100000u

__device__ __forceinline__ unsigned mono_key(float x) {
  unsigned m = __float_as_uint(x);
  return (m & 0x80000000u) ? ~m : (m | 0x80000000u);
}

__global__ __launch_bounds__(TPB)
void detpp_kernel(const float* __restrict__ Cls,
                  const float* __restrict__ Shp,
                  const float* __restrict__ Off,
                  float* __restrict__ Out) {
  __shared__ unsigned long long list[CAP];   // 16 KB survivor list
  __shared__ float det[K_TOP][9];            // stride 9: bank-conflict-free gathers
  __shared__ unsigned long long Mrow[K_TOP]; // adjacency masks (self-bit preset)
  __shared__ unsigned int cnt2;

  const int b = blockIdx.x;
  const int t = threadIdx.x;
  const int lane = t & 63;
  const size_t cbase = (size_t)b * N_ANCH;

  if (t == 0) cnt2 = 0;
  if (t < K_TOP) Mrow[t] = 1ull << t;        // diagonal: (ar == idx) term

  // ---- Phase 1: load Cls (float4); issue before barrier so B1 covers init+loads ----
  const float4* C4 = (const float4*)(Cls + cbase);   // 3456 float4 over 1024 threads
  float4 v0 = C4[t];
  float4 v1 = C4[1024 + t];
  float4 v2 = C4[2048 + t];
  const bool tail = (t < 384);
  float4 v3 = tail ? C4[3072 + t] : make_float4(0.f, 0.f, 0.f, 0.f);
  __syncthreads();                           // B1: cnt2/Mrow init visible

  // keys in registers (16 per thread, sequential access only -> stays in VGPRs)
  unsigned k[16];
  k[0]  = mono_key(v0.x); k[1]  = mono_key(v0.y); k[2]  = mono_key(v0.z); k[3]  = mono_key(v0.w);
  k[4]  = mono_key(v1.x); k[5]  = mono_key(v1.y); k[6]  = mono_key(v1.z); k[7]  = mono_key(v1.w);
  k[8]  = mono_key(v2.x); k[9]  = mono_key(v2.y); k[10] = mono_key(v2.z); k[11] = mono_key(v2.w);
  if (tail) {
    k[12] = mono_key(v3.x); k[13] = mono_key(v3.y); k[14] = mono_key(v3.z); k[15] = mono_key(v3.w);
  } else {
    k[12] = 0u; k[13] = 0u; k[14] = 0u; k[15] = 0u;   // never survive
  }

  int cnt = 0;
  #pragma unroll
  for (int q = 0; q < 16; ++q) cnt += (k[q] > PIVOT_KEY) ? 1 : 0;

  // wave-aggregated compaction: exclusive prefix within wave + one atomic per wave
  int pfx = cnt;
  #pragma unroll
  for (int d = 1; d < 64; d <<= 1) {
    int o = __shfl_up(pfx, d, 64);
    if (lane >= d) pfx += o;
  }
  const int excl = pfx - cnt;
  int wtot = __shfl(pfx, 63, 64);
  unsigned wbase = 0;
  if (lane == 63) wbase = atomicAdd(&cnt2, (unsigned)wtot);
  wbase = (unsigned)__shfl((int)wbase, 63, 64);

  {
    int off = (int)wbase + excl;
    #pragma unroll
    for (int q = 0; q < 16; ++q) {
      if (k[q] > PIVOT_KEY) {
        int base_i = (q < 4) ? (t << 2) : (q < 8) ? ((1024 + t) << 2)
                     : (q < 12) ? ((2048 + t) << 2) : ((3072 + t) << 2);
        int i = base_i + (q & 3);
        if (off < CAP)
          list[off] = ((unsigned long long)k[q] << 32) | (unsigned)(~i);
        off++;
      }
    }
  }
  __syncthreads();                           // B2: list complete

  const unsigned total = cnt2;
  const bool fast = (total >= (unsigned)K_TOP) && (total <= (unsigned)CAP);

  // ---- Phase 2: direct ranking + det build ----
  // Composite keys are unique (index in low bits) -> ranks are a permutation.
  // rank r = #{j : list[j] > mine}; threads with r < 60 build det[r] directly.
  // Matches lax.top_k order: value desc, ties by ascending index.
  auto build_det = [&](unsigned long long e, int r) {
    int i = (int)(~(unsigned)(e & 0xffffffffull));
    unsigned m = (unsigned)(e >> 32);
    unsigned bits = (m & 0x80000000u) ? (m & 0x7fffffffu) : ~m;
    float lg = __uint_as_float(bits);
    float sc = 1.0f / (1.0f + expf(-lg));
    int iz = i / 576;
    int r2 = i - iz * 576;
    int iy = r2 / 24;
    int ix = r2 - iy * 24;
    size_t bb = (size_t)b * 3 * N_ANCH + (size_t)i;
    float o0 = Off[bb], o1 = Off[bb + N_ANCH], o2 = Off[bb + 2 * N_ANCH];
    float s0 = Shp[bb], s1 = Shp[bb + N_ANCH], s2 = Shp[bb + 2 * N_ANCH];
    det[r][0] = 1.0f;
    det[r][1] = sc;
    det[r][2] = ((float)iz + o0) * 4.0f;     // stride = 96/24 = 4
    det[r][3] = ((float)iy + o1) * 4.0f;
    det[r][4] = ((float)ix + o2) * 4.0f;
    det[r][5] = s0;
    det[r][6] = s1;
    det[r][7] = s2;
  };

  if (fast) {
    if (t < (int)total) {
      const unsigned long long e = list[t];
      int r = 0;
      int j = 0;
      const int tot = (int)total;
      for (; j + 4 <= tot; j += 4) {         // same-address broadcast LDS reads
        r += (list[j]     > e) ? 1 : 0;
        r += (list[j + 1] > e) ? 1 : 0;
        r += (list[j + 2] > e) ? 1 : 0;
        r += (list[j + 3] > e) ? 1 : 0;
      }
      for (; j < tot; ++j) r += (list[j] > e) ? 1 : 0;
      if (r < K_TOP) build_det(e, r);
    }
  } else {
    // Exact fallback (never taken on bench data; pivot margin > 8 sigma):
    // brute-force rank of every element over global Cls. Slow but exact.
    for (int i = t; i < N_ANCH; i += TPB) {
      unsigned ki = mono_key(Cls[cbase + i]);
      unsigned long long e = ((unsigned long long)ki << 32) | (unsigned)(~i);
      int r = 0;
      for (int j = 0; j < N_ANCH; ++j) {
        unsigned kj = mono_key(Cls[cbase + j]);
        unsigned long long ej = ((unsigned long long)kj << 32) | (unsigned)(~j);
        r += (ej > e) ? 1 : 0;
      }
      if (r < K_TOP) build_det(e, r);
    }
  }
  __syncthreads();                           // B3: det complete

  // ---- Phase 3: adjacency masks, SYMMETRIC (1800 round-robin pairs, both bits) ----
  // Pair set: (ii, (ii+1+k)%60), k in [0,30). d=30 pairs occur twice -> idempotent OR.
  for (int p = t; p < 1800; p += TPB) {
    int ii = p / 30;
    int kk = p - ii * 30;
    int jj = ii + 1 + kk; if (jj >= 60) jj -= 60;
    float cz1 = det[ii][2], cy1 = det[ii][3], cx1 = det[ii][4];
    float sz1 = det[ii][5], sy1 = det[ii][6], sx1 = det[ii][7];
    float cz2 = det[jj][2], cy2 = det[jj][3], cx2 = det[jj][4];
    float sz2 = det[jj][5], sy2 = det[jj][6], sx2 = det[jj][7];
    float lz1 = cz1 - 0.5f * sz1, hz1 = cz1 + 0.5f * sz1;
    float ly1 = cy1 - 0.5f * sy1, hy1 = cy1 + 0.5f * sy1;
    float lx1 = cx1 - 0.5f * sx1, hx1 = cx1 + 0.5f * sx1;
    float lz2 = cz2 - 0.5f * sz2, hz2 = cz2 + 0.5f * sz2;
    float ly2 = cy2 - 0.5f * sy2, hy2 = cy2 + 0.5f * sy2;
    float lx2 = cx2 - 0.5f * sx2, hx2 = cx2 + 0.5f * sx2;
    float dz = fmaxf(fminf(hz1, hz2) - fmaxf(lz1, lz2), 0.0f);
    float dy = fmaxf(fminf(hy1, hy2) - fmaxf(ly1, ly2), 0.0f);
    float dx = fmaxf(fminf(hx1, hx2) - fmaxf(lx1, lx2), 0.0f);
    float inter = (dz * dy) * dx;
    float v1 = (sz1 * sy1) * sx1;
    float v2 = (sz2 * sy2) * sx2;
    float iouv = inter / (v1 + v2 - inter);
    if (iouv > 0.05f) {
      atomicOr(&Mrow[ii], 1ull << jj);
      atomicOr(&Mrow[jj], 1ull << ii);
    }
  }
  __syncthreads();                           // B4: Mrow complete

  // ---- Phase 4: NMS on wave 0 — scalar chain + (q,c) tree-sum payload ----
  if (t < 64) {
    const bool in = (lane < K_TOP);
    float myscore = in ? det[lane][1] : 0.0f;
    unsigned long long M = in ? Mrow[lane] : 0ull;
    unsigned long long validm = __ballot(in && (myscore > 0.15f));
    unsigned long long suppressed = 0ull;
    float* outb = Out + (size_t)b * K_NMS * 8;
    const int q = lane >> 3, c = lane & 7;

    #pragma unroll
    for (int step = 0; step < K_NMS; ++step) {
      unsigned long long avail = validm & ~suppressed;
      const bool any = (avail != 0ull);
      int idx = any ? (int)__builtin_ctzll(avail) : 0;
      unsigned mlo = (unsigned)__builtin_amdgcn_readlane((int)(unsigned)(M & 0xffffffffull), idx);
      unsigned mhi = (unsigned)__builtin_amdgcn_readlane((int)(unsigned)(M >> 32), idx);
      unsigned long long matched = any ? (avail & (((unsigned long long)mhi << 32) | mlo)) : 0ull;
      int cm = __popcll(matched);
      int top_n = cm < AVG_TOPN ? cm : AVG_TOPN;
      // lane (q,c) reads det[b_q][c]; b_q = q-th set bit of matched (ascending)
      int myb = 0;
      { unsigned long long m2 = matched;
        #pragma unroll
        for (int z = 0; z < 8; ++z) {
          int bz = m2 ? (int)__builtin_ctzll(m2) : 0;
          if (z == q) myb = bz;
          m2 &= m2 - 1ull;
        } }
      float vv = (q < top_n) ? det[myb][c] : 0.0f;
      vv += __shfl_xor(vv, 8, 64);
      vv += __shfl_xor(vv, 16, 64);
      vv += __shfl_xor(vv, 32, 64);
      float sidx = __uint_as_float((unsigned)__builtin_amdgcn_readlane((int)__float_as_uint(myscore), idx));
      float r = vv / (float)(top_n > 0 ? top_n : 1);
      if (lane < 8) {
        float o = r;
        if (lane == 0) o = 1.0f;
        if (lane == 1) o = sidx;
        if (!any) o = -1.0f;
        outb[step * 8 + lane] = o;
      }
      suppressed |= matched;
    }
  }
}

extern "C" void kernel_launch(void* const* d_in, const int* in_sizes, int n_in,
                              void* d_out, int out_size, void* d_ws, size_t ws_size,
                              hipStream_t stream) {
  const float* Cls = (const float*)d_in[0];
  const float* Shp = (const float*)d_in[1];
  const float* Off = (const float*)d_in[2];
  float* Out = (float*)d_out;
  int B = in_sizes[0] / N_ANCH;   // 256
  detpp_kernel<<<B, TPB, 0, stream>>>(Cls, Shp, Off, Out);
}

// Round 8
// 112.769 us; speedup vs baseline: 3.5856x; 1.0446x over previous
//
#include <hip/hip_runtime.h>
#include <math.h>

#define N_ANCH 13824   // 24*24*24
#define TPB 1024
#define K_TOP 60
#define K_NMS 20
#define AVG_TOPN 7
#define CAP 2048       // survivor list capacity (16 KB LDS); overflow -> exact fallback
// Conservative prune pivot: z = 2.25 -> float bits 0x40100000 -> mono key 0xC0100000.
// ~169 +/- 13 survivors/image for N(0,1) logits; needs >=60 and <=CAP, else exact fallback.
#define PIVOT_KEY 0xC0100000u

__device__ __forceinline__ unsigned mono_key(float x) {
  unsigned m = __float_as_uint(x);
  return (m & 0x80000000u) ? ~m : (m | 0x80000000u);
}

__global__ __launch_bounds__(TPB)
void detpp_kernel(const float* __restrict__ Cls,
                  const float* __restrict__ Shp,
                  const float* __restrict__ Off,
                  float* __restrict__ Out) {
  __shared__ __align__(16) unsigned long long list[CAP];   // 16 KB survivor list
  __shared__ float det[K_TOP][9];            // stride 9: bank-conflict-free gathers
  __shared__ unsigned long long Mrow[K_TOP]; // adjacency masks (self-bit preset)
  __shared__ unsigned int cnt2;

  const int b = blockIdx.x;
  const int t = threadIdx.x;
  const int lane = t & 63;
  const size_t cbase = (size_t)b * N_ANCH;

  if (t == 0) cnt2 = 0;
  if (t < K_TOP) Mrow[t] = 1ull << t;        // diagonal: (ar == idx) term

  // ---- Phase 1: load Cls (float4); issue before barrier so B1 covers init+loads ----
  const float4* C4 = (const float4*)(Cls + cbase);   // 3456 float4 over 1024 threads
  float4 v0 = C4[t];
  float4 v1 = C4[1024 + t];
  float4 v2 = C4[2048 + t];
  const bool tail = (t < 384);
  float4 v3 = tail ? C4[3072 + t] : make_float4(0.f, 0.f, 0.f, 0.f);
  __syncthreads();                           // B1: cnt2/Mrow init visible

  unsigned k[16];
  k[0]  = mono_key(v0.x); k[1]  = mono_key(v0.y); k[2]  = mono_key(v0.z); k[3]  = mono_key(v0.w);
  k[4]  = mono_key(v1.x); k[5]  = mono_key(v1.y); k[6]  = mono_key(v1.z); k[7]  = mono_key(v1.w);
  k[8]  = mono_key(v2.x); k[9]  = mono_key(v2.y); k[10] = mono_key(v2.z); k[11] = mono_key(v2.w);
  if (tail) {
    k[12] = mono_key(v3.x); k[13] = mono_key(v3.y); k[14] = mono_key(v3.z); k[15] = mono_key(v3.w);
  } else {
    k[12] = 0u; k[13] = 0u; k[14] = 0u; k[15] = 0u;   // never survive
  }

  int cnt = 0;
  #pragma unroll
  for (int q = 0; q < 16; ++q) cnt += (k[q] > PIVOT_KEY) ? 1 : 0;

  // wave-aggregated compaction: exclusive prefix within wave + one atomic per wave
  int pfx = cnt;
  #pragma unroll
  for (int d = 1; d < 64; d <<= 1) {
    int o = __shfl_up(pfx, d, 64);
    if (lane >= d) pfx += o;
  }
  const int excl = pfx - cnt;
  int wtot = __shfl(pfx, 63, 64);
  unsigned wbase = 0;
  if (lane == 63) wbase = atomicAdd(&cnt2, (unsigned)wtot);
  wbase = (unsigned)__shfl((int)wbase, 63, 64);

  {
    int off = (int)wbase + excl;
    #pragma unroll
    for (int q = 0; q < 16; ++q) {
      if (k[q] > PIVOT_KEY) {
        int base_i = (q < 4) ? (t << 2) : (q < 8) ? ((1024 + t) << 2)
                     : (q < 12) ? ((2048 + t) << 2) : ((3072 + t) << 2);
        int i = base_i + (q & 3);
        if (off < CAP)
          list[off] = ((unsigned long long)k[q] << 32) | (unsigned)(~i);
        off++;
      }
    }
  }
  __syncthreads();                           // B2: list complete

  const unsigned total = cnt2;
  const bool fast = (total >= (unsigned)K_TOP) && (total <= (unsigned)CAP);

  // ---- Phase 2: prefetch gathers, direct ranking, det build from registers ----
  // Composite keys are unique -> ranks are a permutation; r < 60 builds det[r].
  // Matches lax.top_k order: value desc, ties by ascending index.
  if (fast) {
    const int tot = (int)total;
    unsigned long long e = 0ull;
    int i = 0;
    float o0 = 0.f, o1 = 0.f, o2 = 0.f, s0 = 0.f, s1 = 0.f, s2 = 0.f;
    if (t < tot) {
      e = list[t];
      i = (int)(~(unsigned)(e & 0xffffffffull));
      // issue the 6 scattered gathers NOW; latency hides under the ranking loop
      size_t bb = (size_t)b * 3 * N_ANCH + (size_t)i;
      o0 = Off[bb]; o1 = Off[bb + N_ANCH]; o2 = Off[bb + 2 * N_ANCH];
      s0 = Shp[bb]; s1 = Shp[bb + N_ANCH]; s2 = Shp[bb + 2 * N_ANCH];
    }
    if (t < tot) {
      int r = 0;
      const ulonglong2* L2 = (const ulonglong2*)list;
      const int half = tot >> 1;
      for (int j2 = 0; j2 < half; ++j2) {    // b128 same-address broadcast reads
        ulonglong2 p = L2[j2];
        r += (p.x > e) ? 1 : 0;
        r += (p.y > e) ? 1 : 0;
      }
      if (tot & 1) r += (list[tot - 1] > e) ? 1 : 0;
      if (r < K_TOP) {
        unsigned m = (unsigned)(e >> 32);
        unsigned bits = (m & 0x80000000u) ? (m & 0x7fffffffu) : ~m;
        float lg = __uint_as_float(bits);
        int iz = i / 576;
        int r2 = i - iz * 576;
        int iy = r2 / 24;
        int ix = r2 - iy * 24;
        det[r][0] = 1.0f;
        det[r][1] = 1.0f / (1.0f + expf(-lg));
        det[r][2] = ((float)iz + o0) * 4.0f; // stride = 96/24 = 4
        det[r][3] = ((float)iy + o1) * 4.0f;
        det[r][4] = ((float)ix + o2) * 4.0f;
        det[r][5] = s0;
        det[r][6] = s1;
        det[r][7] = s2;
      }
    }
  } else {
    // Exact fallback (never taken on bench data; pivot margin > 8 sigma):
    // brute-force rank of every element over global Cls. Slow but exact.
    for (int i = t; i < N_ANCH; i += TPB) {
      unsigned ki = mono_key(Cls[cbase + i]);
      unsigned long long e = ((unsigned long long)ki << 32) | (unsigned)(~i);
      int r = 0;
      for (int j = 0; j < N_ANCH; ++j) {
        unsigned kj = mono_key(Cls[cbase + j]);
        unsigned long long ej = ((unsigned long long)kj << 32) | (unsigned)(~j);
        r += (ej > e) ? 1 : 0;
      }
      if (r < K_TOP) {
        unsigned m = (unsigned)(e >> 32);
        unsigned bits = (m & 0x80000000u) ? (m & 0x7fffffffu) : ~m;
        float lg = __uint_as_float(bits);
        int iz = i / 576;
        int r2 = i - iz * 576;
        int iy = r2 / 24;
        int ix = r2 - iy * 24;
        size_t bb = (size_t)b * 3 * N_ANCH + (size_t)i;
        det[r][0] = 1.0f;
        det[r][1] = 1.0f / (1.0f + expf(-lg));
        det[r][2] = ((float)iz + Off[bb]) * 4.0f;
        det[r][3] = ((float)iy + Off[bb + N_ANCH]) * 4.0f;
        det[r][4] = ((float)ix + Off[bb + 2 * N_ANCH]) * 4.0f;
        det[r][5] = Shp[bb];
        det[r][6] = Shp[bb + N_ANCH];
        det[r][7] = Shp[bb + 2 * N_ANCH];
      }
    }
  }
  __syncthreads();                           // B3: det complete

  // ---- Phase 3: adjacency masks, SYMMETRIC (1800 round-robin pairs, both bits) ----
  // Pair set: (ii, (ii+1+k)%60), k in [0,30). d=30 pairs occur twice -> idempotent OR.
  for (int p = t; p < 1800; p += TPB) {
    int ii = p / 30;
    int kk = p - ii * 30;
    int jj = ii + 1 + kk; if (jj >= 60) jj -= 60;
    float cz1 = det[ii][2], cy1 = det[ii][3], cx1 = det[ii][4];
    float sz1 = det[ii][5], sy1 = det[ii][6], sx1 = det[ii][7];
    float cz2 = det[jj][2], cy2 = det[jj][3], cx2 = det[jj][4];
    float sz2 = det[jj][5], sy2 = det[jj][6], sx2 = det[jj][7];
    float lz1 = cz1 - 0.5f * sz1, hz1 = cz1 + 0.5f * sz1;
    float ly1 = cy1 - 0.5f * sy1, hy1 = cy1 + 0.5f * sy1;
    float lx1 = cx1 - 0.5f * sx1, hx1 = cx1 + 0.5f * sx1;
    float lz2 = cz2 - 0.5f * sz2, hz2 = cz2 + 0.5f * sz2;
    float ly2 = cy2 - 0.5f * sy2, hy2 = cy2 + 0.5f * sy2;
    float lx2 = cx2 - 0.5f * sx2, hx2 = cx2 + 0.5f * sx2;
    float dz = fmaxf(fminf(hz1, hz2) - fmaxf(lz1, lz2), 0.0f);
    float dy = fmaxf(fminf(hy1, hy2) - fmaxf(ly1, ly2), 0.0f);
    float dx = fmaxf(fminf(hx1, hx2) - fmaxf(lx1, lx2), 0.0f);
    float inter = (dz * dy) * dx;
    float v1 = (sz1 * sy1) * sx1;
    float v2 = (sz2 * sy2) * sx2;
    float iouv = inter / (v1 + v2 - inter);
    if (iouv > 0.05f) {
      atomicOr(&Mrow[ii], 1ull << jj);
      atomicOr(&Mrow[jj], 1ull << ii);
    }
  }
  __syncthreads();                           // B4: Mrow complete

  // ---- Phase 4: NMS — waves 0-2 redundantly run the cheap mask chain; each lane
  //      captures its (step, column) slice and computes the payload in parallel. ----
  const int w = t >> 6;
  if (w < 3) {
    const bool in = (lane < K_TOP);
    float myscore = in ? det[lane][1] : 0.0f;
    unsigned long long M = in ? Mrow[lane] : 0ull;
    unsigned long long validm = __ballot(in && (myscore > 0.15f));
    unsigned long long suppressed = 0ull;
    float* outb = Out + (size_t)b * K_NMS * 8;

    const int my_s = (w << 3) + (lane >> 3);   // wave0: steps 0-7, wave1: 8-15, wave2: 16-23
    const int c = lane & 7;
    const bool active = (my_s < K_NMS);
    unsigned long long my_matched = 0ull;
    int my_idx = 0;
    bool my_any = false;

    #pragma unroll
    for (int step = 0; step < K_NMS; ++step) {
      unsigned long long avail = validm & ~suppressed;   // wave-uniform chain
      const bool any = (avail != 0ull);
      int idx = any ? (int)__builtin_ctzll(avail) : 0;
      unsigned mlo = (unsigned)__builtin_amdgcn_readlane((int)(unsigned)(M & 0xffffffffull), idx);
      unsigned mhi = (unsigned)__builtin_amdgcn_readlane((int)(unsigned)(M >> 32), idx);
      unsigned long long matched = any ? (avail & (((unsigned long long)mhi << 32) | mlo)) : 0ull;
      if (step == my_s) { my_matched = matched; my_idx = idx; my_any = any; }
      suppressed |= matched;
    }

    if (active) {
      int cm = __popcll(my_matched);
      int top_n = cm < AVG_TOPN ? cm : AVG_TOPN;
      float sum = 0.0f;
      unsigned long long mm = my_matched;
      #pragma unroll
      for (int q = 0; q < AVG_TOPN; ++q) {     // ascending-index accumulation
        int bq = mm ? (int)__builtin_ctzll(mm) : 0;
        if (q < top_n) sum += det[bq][c];
        mm &= mm - 1ull;
      }
      float r = sum / (float)(top_n > 0 ? top_n : 1);
      if (c == 0) r = 1.0f;
      if (c == 1) r = det[my_idx][1];
      if (!my_any) r = -1.0f;
      outb[my_s * 8 + c] = r;
    }
  }
}

extern "C" void kernel_launch(void* const* d_in, const int* in_sizes, int n_in,
                              void* d_out, int out_size, void* d_ws, size_t ws_size,
                              hipStream_t stream) {
  const float* Cls = (const float*)d_in[0];
  const float* Shp = (const float*)d_in[1];
  const float* Off = (const float*)d_in[2];
  float* Out = (float*)d_out;
  int B = in_sizes[0] / N_ANCH;   // 256
  detpp_kernel<<<B, TPB, 0, stream>>>(Cls, Shp, Off, Out);
}